// Round 3
// baseline (997.057 us; speedup 1.0000x reference)
//
#include <hip/hip_runtime.h>
#include <hip/hip_bf16.h>
#include <math.h>

// Problem constants (from reference)
#define DM   1024        // d_model
#define DI   2048        // d_inner
#define DS   16          // d_state
#define DTR  64          // dt_rank
#define NB   2           // batch
#define LL   1024        // seq len
#define MR   (NB*LL)     // 2048 rows (b*l flattened)
#define XDBL 96          // dt_rank + 2*d_state
#define NC   32          // scan chunks
#define CL   32          // chunk length (NC*CL == LL)
#define GRID 512
#define NTH  256

typedef _Float16 half8  __attribute__((ext_vector_type(8)));
typedef _Float16 half4v __attribute__((ext_vector_type(4)));
typedef float    floatx4 __attribute__((ext_vector_type(4)));

__device__ __forceinline__ void gload_lds16(const void* g, void* l) {
  __builtin_amdgcn_global_load_lds(
      (const __attribute__((address_space(1))) void*)g,
      (__attribute__((address_space(3))) void*)l, 16, 0, 0);
}

// ---------------------------------------------------------------------------
// Manual grid barrier (regular launch; no hipLaunchCooperativeKernel, which
// the harness's graph capture rejected in R2 -> kernel never ran).
// bar[0] = arrive count, bar[1] = generation. Agent-scope acq/rel atomics
// (cross-XCD correct; same construction as ROCm's grid_group::sync).
// Residency guarantee: 64 KB LDS + __launch_bounds__(256,2) => exactly
// 2 blocks/CU, 512 blocks == 512 slots. Spin is BOUNDED so a residency
// failure shows as wrong output, not a hang.
// ---------------------------------------------------------------------------
__device__ __forceinline__ void gsync(unsigned* bar) {
  __syncthreads();
  if (threadIdx.x == 0) {
    unsigned gen = __hip_atomic_load(bar + 1, __ATOMIC_RELAXED,
                                     __HIP_MEMORY_SCOPE_AGENT);
    unsigned prev = __hip_atomic_fetch_add(bar, 1u, __ATOMIC_ACQ_REL,
                                           __HIP_MEMORY_SCOPE_AGENT);
    if (prev == (unsigned)(GRID - 1)) {
      __hip_atomic_store(bar, 0u, __ATOMIC_RELAXED, __HIP_MEMORY_SCOPE_AGENT);
      __hip_atomic_fetch_add(bar + 1, 1u, __ATOMIC_RELEASE,
                             __HIP_MEMORY_SCOPE_AGENT);
    } else {
      for (long long i = 0; i < (1LL << 24); i++) {
        if (__hip_atomic_load(bar + 1, __ATOMIC_ACQUIRE,
                              __HIP_MEMORY_SCOPE_AGENT) != gen) break;
        __builtin_amdgcn_s_sleep(2);
      }
    }
  }
  __syncthreads();
}

struct MegaArgs {
  const float* x; const float* ln_w; const float* ln_b;
  const float* w_in; const float* w_out; const float* w_xp; const float* w_dt;
  const float* conv_w; const float* conv_b; const float* dt_proj_b;
  const float* A_log; const float* Dvec;
  _Float16* h_h; _Float16* w_in_h; _Float16* w_out_h; _Float16* w_xp_h;
  _Float16* w_dt_h;
  _Float16* xin; _Float16* z; _Float16* xc; _Float16* dtb; _Float16* dtr;
  _Float16* xp_part; _Float16* out_part; _Float16* y;
  float* x_dbl; float* SA; float* HE; float* out;
  unsigned* bar;
};

// ---------------------------------------------------------------------------
// MFMA f16 GEMM phase (device fn) — R13's verified counted-vmcnt depth-3
// pipeline. C[m,n] = sum_k A[m,k]*W[n,k], fp32 acc. Tile 128 x TN.
// 4 LDS buffers of 32-wide slabs; prologue stages 3; per iter:
//   vmcnt(2*LPS) -> s_barrier -> ds_read+MFMA(setprio) -> stage(i+3).
// EPI 0: dual f16 store (n<DI -> Cv else C2v, compact DI-wide rows)
// EPI 4: f16 partial store at Cv + bz*M*ldc (split-K, no atomics)
// EPI 5: f16 store softplus(acc + extra[n])
// ---------------------------------------------------------------------------
template <int EPI, int TN>
__device__ __forceinline__ void gemm_phase(
    const _Float16* __restrict__ A, const _Float16* __restrict__ W,
    void* __restrict__ Cv, void* __restrict__ C2v,
    const float* __restrict__ extra, int ldc,
    int M, int N, int K, int kchunk, int bx, int by, int bz,
    _Float16 (&As)[4][4096], _Float16 (&Ws)[4][4096]) {
  constexpr int NT = (TN + 31) / 32;
  constexpr int WSLOT = TN / 16;
  constexpr int LPS = 2 + (WSLOT >= 8 ? 2 : 1);
  const int t = threadIdx.x;
  const int wave = t >> 6, lane = t & 63;
  const int m0 = by * 128, n0 = bx * TN;
  const int k_beg = bz * kchunk;
  const int nk = kchunk / 32;
  const int wm = (wave >> 1) * 64, wn = (wave & 1) * (TN / 2);
  floatx4 acc[4][NT];
#pragma unroll
  for (int i = 0; i < 4; i++)
#pragma unroll
    for (int j = 0; j < NT; j++) acc[i][j] = {0.f, 0.f, 0.f, 0.f};

  const int fr = lane & 15;
  const int kc8 = lane >> 4;
  const int kp = (kc8 ^ ((fr >> 1) & 3)) * 8;   // XOR bank swizzle

  auto stage = [&](int buf, int k0) {
    for (int sl = wave; sl < 8; sl += 4) {
      const int idx = sl * 64 + lane;
      const int row = idx >> 2;
      const int kc = (idx & 3) ^ ((row >> 1) & 3);
      gload_lds16(A + (size_t)(m0 + row) * K + k0 + kc * 8, &As[buf][sl * 512]);
    }
    for (int sl = wave; sl < WSLOT; sl += 4) {
      const int idx = sl * 64 + lane;
      const int row = idx >> 2;
      const int kc = (idx & 3) ^ ((row >> 1) & 3);
      const int wrow = (n0 + row < N) ? row : 0;
      gload_lds16(W + (size_t)(n0 + wrow) * K + k0 + kc * 8, &Ws[buf][sl * 512]);
    }
  };

  const int npre = nk < 3 ? nk : 3;
  for (int p = 0; p < npre; p++) stage(p, k_beg + p * 32);

  for (int ki = 0; ki < nk; ki++) {
    const int rem = nk - 1 - ki;
    if (rem >= 2)
      asm volatile("s_waitcnt vmcnt(%0)" :: "n"(2 * LPS) : "memory");
    else if (rem == 1)
      asm volatile("s_waitcnt vmcnt(%0)" :: "n"(LPS) : "memory");
    else
      asm volatile("s_waitcnt vmcnt(0)" ::: "memory");
    __builtin_amdgcn_s_barrier();
    const int cur = ki & 3;
    half8 af[4], wf[NT];
#pragma unroll
    for (int i = 0; i < 4; i++)
      af[i] = *(const half8*)&As[cur][(wm + i * 16 + fr) * 32 + kp];
#pragma unroll
    for (int j = 0; j < NT; j++)
      wf[j] = *(const half8*)&Ws[cur][(wn + j * 16 + fr) * 32 + kp];
    __builtin_amdgcn_s_setprio(1);
#pragma unroll
    for (int i = 0; i < 4; i++)
#pragma unroll
      for (int j = 0; j < NT; j++)
        acc[i][j] = __builtin_amdgcn_mfma_f32_16x16x32_f16(af[i], wf[j], acc[i][j], 0, 0, 0);
    __builtin_amdgcn_s_setprio(0);
    if (ki + 3 < nk) stage((ki + 3) & 3, k_beg + (ki + 3) * 32);
  }

  const int col = lane & 15, rowq = lane >> 4;
#pragma unroll
  for (int i = 0; i < 4; i++) {
#pragma unroll
    for (int j = 0; j < NT; j++) {
      const int n = n0 + wn + j * 16 + col;
      if (n < N) {
#pragma unroll
        for (int r = 0; r < 4; r++) {
          const int m = m0 + wm + i * 16 + rowq * 4 + r;
          float v = acc[i][j][r];
          if (EPI == 0) {
            if (n < DI) ((_Float16*)Cv )[(size_t)m * DI + n]      = (_Float16)v;
            else        ((_Float16*)C2v)[(size_t)m * DI + n - DI] = (_Float16)v;
          } else if (EPI == 4) {
            ((_Float16*)Cv)[((size_t)bz * M + m) * ldc + n] = (_Float16)v;
          } else if (EPI == 5) {
            v += extra[n];
            v = (v > 20.f) ? v : __logf(1.f + __expf(v));
            ((_Float16*)Cv)[(size_t)m * ldc + n] = (_Float16)v;
          }
        }
      }
    }
  }
}

// ---------------------------------------------------------------------------
// Load per-channel A row; detect S4D-real init a[s] == -(s+1) (uniform).
// ---------------------------------------------------------------------------
__device__ __forceinline__ bool load_a(const float* __restrict__ A_log, int d,
                                       float* a) {
  const float4* Ap = (const float4*)(A_log + (size_t)d * DS);
  bool fast = true;
#pragma unroll
  for (int i = 0; i < 4; i++) {
    float4 v = Ap[i];
    a[4 * i + 0] = -__expf(v.x); a[4 * i + 1] = -__expf(v.y);
    a[4 * i + 2] = -__expf(v.z); a[4 * i + 3] = -__expf(v.w);
  }
#pragma unroll
  for (int s = 0; s < DS; s++)
    fast = fast && (fabsf(a[s] + (float)(s + 1)) < 1e-4f);
  return fast;
}

// ---------------------------------------------------------------------------
// R15 megakernel: whole MambaBlock, ONE regular launch + manual grid barrier.
// 512 blocks x 256 threads, 64 KB LDS -> exactly 2 blocks/CU (all resident).
// ---------------------------------------------------------------------------
__global__ __launch_bounds__(256, 2) void mega(MegaArgs P) {
  __shared__ alignas(16) _Float16 As[4][4096];   // 32 KB
  __shared__ alignas(16) _Float16 Ws[4][4096];   // 32 KB
  const int bid = blockIdx.x;
  const int t = threadIdx.x;

  // ---- P0: LayerNorm (grid-stride rows) + weight f2h ----
  {
    float* sAB = (float*)&Ws[0][0];   // 8 floats scratch
    for (int r = bid; r < MR; r += GRID) {
      const float* xr = P.x + (size_t)r * DM;
      float s = 0.f, ss = 0.f;
      for (int i = t; i < DM; i += NTH) {
        float v = xr[i];
        s += v; ss += v * v;
      }
      for (int o = 32; o > 0; o >>= 1) {
        s  += __shfl_down(s, o, 64);
        ss += __shfl_down(ss, o, 64);
      }
      const int wid = t >> 6, lid = t & 63;
      if (lid == 0) { sAB[wid] = s; sAB[4 + wid] = ss; }
      __syncthreads();
      if (t == 0) {
        float S  = sAB[0] + sAB[1] + sAB[2] + sAB[3];
        float SS = sAB[4] + sAB[5] + sAB[6] + sAB[7];
        float mu = S / DM;
        sAB[0] = mu;
        sAB[4] = rsqrtf(SS / DM - mu * mu + 1e-5f);
      }
      __syncthreads();
      const float mu = sAB[0], rs = sAB[4];
      for (int i = t; i < DM; i += NTH)
        P.h_h[(size_t)r * DM + i] = (_Float16)((xr[i] - mu) * rs * P.ln_w[i] + P.ln_b[i]);
      __syncthreads();   // protect sAB before next row's writes
    }
    const int N0 = 1048576, N1 = 524288, N2 = 49152, N3 = 32768;
    for (int i = bid * NTH + t; i < N0 + N1 + N2 + N3; i += GRID * NTH) {
      const float* s; _Float16* d; int off;
      if (i < N0)              { s = P.w_in;  d = P.w_in_h;  off = i; }
      else if (i < N0+N1)      { s = P.w_out; d = P.w_out_h; off = i - N0; }
      else if (i < N0+N1+N2)   { s = P.w_xp;  d = P.w_xp_h;  off = i - N0 - N1; }
      else                     { s = P.w_dt;  d = P.w_dt_h;  off = i - N0 - N1 - N2; }
      float4 v = ((const float4*)s)[off];
      half4v h = {(_Float16)v.x, (_Float16)v.y, (_Float16)v.z, (_Float16)v.w};
      ((half4v*)d)[off] = h;
    }
  }
  gsync(P.bar);

  // ---- P1: in_proj GEMM (grid (32,16)) ----
  gemm_phase<0, 128>(P.h_h, P.w_in_h, P.xin, P.z, nullptr, 0,
                     MR, 2 * DI, DM, DM, bid & 31, bid >> 5, 0, As, Ws);
  gsync(P.bar);

  // ---- P2: depthwise causal conv1d + SiLU (8 ch/thread) ----
  for (int idx = bid * NTH + t; idx < MR * DI / 8; idx += GRID * NTH) {
    const int d8 = idx & (DI / 8 - 1);
    const int ml = idx >> 8;
    const int l  = ml & (LL - 1);
    const int d0 = d8 * 8;
    half8 xr[4];
    const half8 zero = {0, 0, 0, 0, 0, 0, 0, 0};
#pragma unroll
    for (int k = 0; k < 4; k++) {
      const int lp = l - 3 + k;
      xr[k] = (lp >= 0) ? *(const half8*)&P.xin[(size_t)(ml - 3 + k) * DI + d0] : zero;
    }
    half8 o;
#pragma unroll
    for (int j = 0; j < 8; j++) {
      float acc = P.conv_b[d0 + j];
#pragma unroll
      for (int k = 0; k < 4; k++)
        acc += (float)xr[k][j] * P.conv_w[(d0 + j) * 4 + k];
      o[j] = (_Float16)(acc / (1.f + __expf(-acc)));
    }
    *(half8*)&P.xc[(size_t)ml * DI + d0] = o;
  }
  gsync(P.bar);

  // ---- P3: x_proj GEMM (grid (1,16,16), split-K 16; half the blocks) ----
  if (bid < 256)
    gemm_phase<4, 96>(P.xc, P.w_xp_h, P.xp_part, nullptr, nullptr, XDBL,
                      MR, XDBL, DI, DI / 16, 0, bid & 15, bid >> 4, As, Ws);
  gsync(P.bar);

  // ---- P4: x_proj partial reduce (f32 x_dbl + f16 dtr) ----
  for (int idx = bid * NTH + t; idx < MR * XDBL; idx += GRID * NTH) {
    const int m = idx / XDBL, c = idx - m * XDBL;
    float s = 0.f;
#pragma unroll
    for (int zz = 0; zz < 16; zz++)
      s += (float)P.xp_part[(size_t)zz * (MR * XDBL) + idx];
    P.x_dbl[idx] = s;
    if (c < DTR) P.dtr[m * DTR + c] = (_Float16)s;
  }
  gsync(P.bar);

  // ---- P5: dt GEMM + softplus (grid (32,16)) ----
  gemm_phase<5, 64>(P.dtr, P.w_dt_h, P.dtb, nullptr, P.dt_proj_b, DI,
                    MR, DI, DTR, DTR, bid & 31, bid >> 5, 0, As, Ws);
  gsync(P.bar);

  // ---- P6: scan phase 1 (local chunk scans) ----
  {
    float (*Bs)[DS] = (float(*)[DS])&As[0][0];   // 2 KB
    const int dblk = bid & 7;
    const int c = (bid >> 3) & (NC - 1);
    const int b = bid >> 8;
    const int d = dblk * 256 + t;
    const int mlbase = b * LL + c * CL;
    for (int i = t; i < CL * DS; i += NTH) {
      int tt = i >> 4, s = i & 15;
      Bs[tt][s] = P.x_dbl[(size_t)(mlbase + tt) * XDBL + DTR + s];
    }
    float a[DS];
    const bool fast = load_a(P.A_log, d, a);
    float h[DS];
#pragma unroll
    for (int s = 0; s < DS; s++) h[s] = 0.f;
    float S = 0.f;
    __syncthreads();
    if (fast) {
      for (int tt = 0; tt < CL; tt++) {
        const size_t ml = mlbase + tt;
        const float dtv = (float)P.dtb[ml * DI + d];
        const float u   = (float)P.xc[ml * DI + d];
        const float du  = dtv * u;
        S += dtv;
        const float r = __expf(-dtv);
        float Pp = 1.f;
#pragma unroll
        for (int s = 0; s < DS; s++) {
          Pp *= r;
          h[s] = Pp * h[s] + du * Bs[tt][s];
        }
      }
    } else {
      for (int tt = 0; tt < CL; tt++) {
        const size_t ml = mlbase + tt;
        const float dtv = (float)P.dtb[ml * DI + d];
        const float u   = (float)P.xc[ml * DI + d];
        const float du  = dtv * u;
        S += dtv;
#pragma unroll
        for (int s = 0; s < DS; s++)
          h[s] = __expf(dtv * a[s]) * h[s] + du * Bs[tt][s];
      }
    }
    const size_t base = ((size_t)(b * NC + c) * DS) * DI + d;
#pragma unroll
    for (int s = 0; s < DS; s++) P.HE[base + (size_t)s * DI] = h[s];
    P.SA[(size_t)(b * NC + c) * DI + d] = S;
  }
  gsync(P.bar);

  // ---- P7: scan phase 2 (sequential chunk combine; 256 blocks' work) ----
  if (bid < 256) {
    const int idx = bid * NTH + t;    // NB*DS*DI = 65536
    const int d = idx & (DI - 1);
    const int s = (idx >> 11) & (DS - 1);
    const int b = idx >> 15;
    const float a = -__expf(P.A_log[(size_t)d * DS + s]);
    float Hc = 0.f;
    for (int c = 0; c < NC; c++) {
      const size_t o = ((size_t)(b * NC + c) * DS + s) * DI + d;
      const float he = P.HE[o];
      const float Pp = __expf(a * P.SA[(size_t)(b * NC + c) * DI + d]);
      P.HE[o] = Hc;
      Hc = Pp * Hc + he;
    }
  }
  gsync(P.bar);

  // ---- P8: scan phase 3 (carry-in re-scan + fused y output) ----
  {
    float (*Bs)[DS] = (float(*)[DS])&As[0][0];
    float (*Cs)[DS] = (float(*)[DS])((char*)&As[0][0] + 2048);
    const int dblk = bid & 7;
    const int c = (bid >> 3) & (NC - 1);
    const int b = bid >> 8;
    const int d = dblk * 256 + t;
    const int mlbase = b * LL + c * CL;
    for (int i = t; i < CL * DS; i += NTH) {
      int tt = i >> 4, s = i & 15;
      const size_t ro = (size_t)(mlbase + tt) * XDBL + DTR + s;
      Bs[tt][s] = P.x_dbl[ro];
      Cs[tt][s] = P.x_dbl[ro + DS];
    }
    float a[DS];
    const bool fast = load_a(P.A_log, d, a);
    float h[DS];
    const size_t base = ((size_t)(b * NC + c) * DS) * DI + d;
#pragma unroll
    for (int s = 0; s < DS; s++) h[s] = P.HE[base + (size_t)s * DI];
    const float Dv = P.Dvec[d];
    __syncthreads();
    if (fast) {
      for (int tt = 0; tt < CL; tt++) {
        const size_t ml = mlbase + tt;
        const float dtv = (float)P.dtb[ml * DI + d];
        const float u   = (float)P.xc[ml * DI + d];
        const float du  = dtv * u;
        const float r = __expf(-dtv);
        float Pp = 1.f, p = 0.f;
#pragma unroll
        for (int s = 0; s < DS; s++) {
          Pp *= r;
          h[s] = Pp * h[s] + du * Bs[tt][s];
          p += h[s] * Cs[tt][s];
        }
        const float zv = (float)P.z[ml * DI + d];
        const float sil = zv / (1.f + __expf(-zv));
        P.y[ml * DI + d] = (_Float16)((p + u * Dv) * sil);
      }
    } else {
      for (int tt = 0; tt < CL; tt++) {
        const size_t ml = mlbase + tt;
        const float dtv = (float)P.dtb[ml * DI + d];
        const float u   = (float)P.xc[ml * DI + d];
        const float du  = dtv * u;
        float p = 0.f;
#pragma unroll
        for (int s = 0; s < DS; s++) {
          h[s] = __expf(dtv * a[s]) * h[s] + du * Bs[tt][s];
          p += h[s] * Cs[tt][s];
        }
        const float zv = (float)P.z[ml * DI + d];
        const float sil = zv / (1.f + __expf(-zv));
        P.y[ml * DI + d] = (_Float16)((p + u * Dv) * sil);
      }
    }
  }
  gsync(P.bar);

  // ---- P9: out_proj GEMM (grid (8,16,4), split-K 4) ----
  gemm_phase<4, 128>(P.y, P.w_out_h, P.out_part, nullptr, nullptr, DM,
                     MR, DM, DI, DI / 4, bid & 7, (bid >> 3) & 15, bid >> 7, As, Ws);
  gsync(P.bar);

  // ---- P10: residual + partial reduce ----
  for (int i = bid * NTH + t; i < MR * DM / 4; i += GRID * NTH) {
    float4 v = ((const float4*)P.x)[i];
#pragma unroll
    for (int zz = 0; zz < 4; zz++) {
      half4v p = ((const half4v*)(P.out_part + (size_t)zz * MR * DM))[i];
      v.x += (float)p.x; v.y += (float)p.y; v.z += (float)p.z; v.w += (float)p.w;
    }
    ((float4*)P.out)[i] = v;
  }
}

// ---------------------------------------------------------------------------
// Launch: memset barrier state + single regular dispatch.
// ---------------------------------------------------------------------------
extern "C" void kernel_launch(void* const* d_in, const int* in_sizes, int n_in,
                              void* d_out, int out_size, void* d_ws, size_t ws_size,
                              hipStream_t stream) {
  const float* x         = (const float*)d_in[0];
  const float* ln_w      = (const float*)d_in[1];
  const float* ln_b      = (const float*)d_in[2];
  const float* in_proj_w = (const float*)d_in[3];   // (4096, 1024)
  const float* conv_w    = (const float*)d_in[4];   // (2048, 1, 4)
  const float* conv_b    = (const float*)d_in[5];
  const float* x_proj_w  = (const float*)d_in[6];   // (96, 2048)
  const float* dt_proj_w = (const float*)d_in[7];   // (2048, 64)
  const float* dt_proj_b = (const float*)d_in[8];
  const float* A_log     = (const float*)d_in[9];   // (2048, 16)
  const float* Dvec      = (const float*)d_in[10];
  const float* out_proj_w= (const float*)d_in[11];  // (1024, 2048)
  float* out = (float*)d_out;

  // workspace layout (bytes). Aliasing:
  //   y aliases xin (xin dead after conv/P2; y written P8, read P9)
  //   xp_part aliases xin too (lives only P3->P4, inside xin's dead window)
  //   out_part aliases dtb (dtb dead after P8)
  // Barrier state sits in the freed tail at 69337088 (within the ws extent
  // the R13 layout already proved allocated).
  char* ws = (char*)d_ws;
  _Float16* h_h      = (_Float16*)ws;                 //  4 MB
  _Float16* xin_h    = (_Float16*)(ws + 4194304);     //  8 MB
  _Float16* y_h      = xin_h;
  _Float16* xp_part  = xin_h;                         //  6 MB (16 x MR x 96 f16)
  _Float16* z_h      = (_Float16*)(ws + 12582912);    //  8 MB
  _Float16* xc_h     = (_Float16*)(ws + 20971520);    //  8 MB
  _Float16* dtb_h    = (_Float16*)(ws + 29360128);    //  8 MB
  _Float16* out_part = dtb_h;                         // 16 MB (4 x MR*DM f16)
  float*    x_dbl    = (float*)   (ws + 46137344);    //  0.75 MB
  float*    SA       = (float*)   (ws + 46923776);    //  0.5 MB
  _Float16* dtr_h    = (_Float16*)(ws + 47448064);    //  0.25 MB
  float*    HE       = (float*)   (ws + 47710208);    //  8 MB
  _Float16* w_in_h   = (_Float16*)(ws + 56098816);    //  8 MB
  _Float16* w_out_h  = (_Float16*)(ws + 64487424);    //  4 MB
  _Float16* w_xp_h   = (_Float16*)(ws + 68681728);    //  0.375 MB
  _Float16* w_dt_h   = (_Float16*)(ws + 69074944);    //  0.25 MB
  unsigned* bar      = (unsigned*)(ws + 69337088);    //  128 B barrier state

  hipMemsetAsync(bar, 0, 128, stream);

  MegaArgs P;
  P.x = x; P.ln_w = ln_w; P.ln_b = ln_b;
  P.w_in = in_proj_w; P.w_out = out_proj_w; P.w_xp = x_proj_w; P.w_dt = dt_proj_w;
  P.conv_w = conv_w; P.conv_b = conv_b; P.dt_proj_b = dt_proj_b;
  P.A_log = A_log; P.Dvec = Dvec;
  P.h_h = h_h; P.w_in_h = w_in_h; P.w_out_h = w_out_h; P.w_xp_h = w_xp_h;
  P.w_dt_h = w_dt_h;
  P.xin = xin_h; P.z = z_h; P.xc = xc_h; P.dtb = dtb_h; P.dtr = dtr_h;
  P.xp_part = xp_part; P.out_part = out_part; P.y = y_h;
  P.x_dbl = x_dbl; P.SA = SA; P.HE = HE; P.out = out;
  P.bar = bar;

  mega<<<dim3(GRID), dim3(NTH), 0, stream>>>(P);
}

// Round 4
// 425.834 us; speedup vs baseline: 2.3414x; 2.3414x over previous
//
#include <hip/hip_runtime.h>
#include <hip/hip_bf16.h>
#include <math.h>

// Problem constants (from reference)
#define DM   1024        // d_model
#define DI   2048        // d_inner
#define DS   16          // d_state
#define DTR  64          // dt_rank
#define NB   2           // batch
#define LL   1024        // seq len
#define MR   (NB*LL)     // 2048 rows (b*l flattened)
#define XDBL 96          // dt_rank + 2*d_state
#define NC   32          // scan chunks
#define CL   32          // chunk length (NC*CL == LL)
#define GRID 512
#define NTH  256

typedef _Float16 half8  __attribute__((ext_vector_type(8)));
typedef _Float16 half4v __attribute__((ext_vector_type(4)));
typedef float    floatx4 __attribute__((ext_vector_type(4)));

__device__ __forceinline__ void gload_lds16(const void* g, void* l) {
  __builtin_amdgcn_global_load_lds(
      (const __attribute__((address_space(1))) void*)g,
      (__attribute__((address_space(3))) void*)l, 16, 0, 0);
}

// ---------------------------------------------------------------------------
// R16 grid barrier — contention-free flag design.
// R3's single fetch_add counter serialized 512 cross-XCD RMWs on one line
// (~165 ns each = ~85 us/barrier -> 925 us kernel). Here:
//   arrival : block i release-stores flags[i] = phase   (512 distinct words)
//   gather  : block 0's 256 threads poll 2 flags each (relaxed), fence
//   release : block 0 thread 0 release-stores gen = phase
//   wait    : other blocks spin relaxed on gen (+ s_sleep), fence
// Happens-before: data -> rel(flag_i) -> b0 obs + fence -> rel(gen) ->
// waiter obs + fence -> data reads. Spins bounded => failure = wrong
// output, never a hang.
// ---------------------------------------------------------------------------
__device__ __forceinline__ void gsync(unsigned* bar, unsigned phase) {
  __syncthreads();
  unsigned* gen   = bar + 1;
  unsigned* flags = bar + 64;
  const int bid = blockIdx.x;
  const int t = threadIdx.x;
  if (bid == 0) {
    for (int i = t; i < GRID; i += NTH) {
      if (i) {
        long long guard = 0;
        while (__hip_atomic_load(&flags[i], __ATOMIC_RELAXED,
                                 __HIP_MEMORY_SCOPE_AGENT) < phase &&
               ++guard < (1LL << 20))
          __builtin_amdgcn_s_sleep(1);
      }
    }
    __threadfence();
    __syncthreads();
    if (t == 0)
      __hip_atomic_store(gen, phase, __ATOMIC_RELEASE, __HIP_MEMORY_SCOPE_AGENT);
  } else {
    if (t == 0) {
      __hip_atomic_store(&flags[bid], phase, __ATOMIC_RELEASE,
                         __HIP_MEMORY_SCOPE_AGENT);
      long long guard = 0;
      while (__hip_atomic_load(gen, __ATOMIC_RELAXED,
                               __HIP_MEMORY_SCOPE_AGENT) < phase &&
             ++guard < (1LL << 20))
        __builtin_amdgcn_s_sleep(1);
      __threadfence();
    }
    __syncthreads();
  }
}

struct MegaArgs {
  const float* x; const float* ln_w; const float* ln_b;
  const float* w_in; const float* w_out; const float* w_xp; const float* w_dt;
  const float* conv_w; const float* conv_b; const float* dt_proj_b;
  const float* A_log; const float* Dvec;
  _Float16* h_h; _Float16* w_in_h; _Float16* w_out_h; _Float16* w_xp_h;
  _Float16* w_dt_h;
  _Float16* xin; _Float16* z; _Float16* xc; _Float16* dtb; _Float16* dtr;
  _Float16* xp_part; _Float16* out_part; _Float16* y;
  float* x_dbl; float* SA; float* HE; float* out;
  unsigned* bar;
};

// ---------------------------------------------------------------------------
// MFMA f16 GEMM phase (device fn) — R13's verified counted-vmcnt depth-3
// pipeline. C[m,n] = sum_k A[m,k]*W[n,k], fp32 acc. Tile 128 x TN.
// 4 LDS buffers of 32-wide slabs; prologue stages 3; per iter:
//   vmcnt(2*LPS) -> s_barrier -> ds_read+MFMA(setprio) -> stage(i+3).
// EPI 0: dual f16 store (n<DI -> Cv else C2v, compact DI-wide rows)
// EPI 4: f16 partial store at Cv + bz*M*ldc (split-K, no atomics)
// EPI 5: f16 store softplus(acc + extra[n])
// ---------------------------------------------------------------------------
template <int EPI, int TN>
__device__ __forceinline__ void gemm_phase(
    const _Float16* __restrict__ A, const _Float16* __restrict__ W,
    void* __restrict__ Cv, void* __restrict__ C2v,
    const float* __restrict__ extra, int ldc,
    int M, int N, int K, int kchunk, int bx, int by, int bz,
    _Float16 (&As)[4][4096], _Float16 (&Ws)[4][4096]) {
  constexpr int NT = (TN + 31) / 32;
  constexpr int WSLOT = TN / 16;
  constexpr int LPS = 2 + (WSLOT >= 8 ? 2 : 1);
  const int t = threadIdx.x;
  const int wave = t >> 6, lane = t & 63;
  const int m0 = by * 128, n0 = bx * TN;
  const int k_beg = bz * kchunk;
  const int nk = kchunk / 32;
  const int wm = (wave >> 1) * 64, wn = (wave & 1) * (TN / 2);
  floatx4 acc[4][NT];
#pragma unroll
  for (int i = 0; i < 4; i++)
#pragma unroll
    for (int j = 0; j < NT; j++) acc[i][j] = {0.f, 0.f, 0.f, 0.f};

  const int fr = lane & 15;
  const int kc8 = lane >> 4;
  const int kp = (kc8 ^ ((fr >> 1) & 3)) * 8;   // XOR bank swizzle

  auto stage = [&](int buf, int k0) {
    for (int sl = wave; sl < 8; sl += 4) {
      const int idx = sl * 64 + lane;
      const int row = idx >> 2;
      const int kc = (idx & 3) ^ ((row >> 1) & 3);
      gload_lds16(A + (size_t)(m0 + row) * K + k0 + kc * 8, &As[buf][sl * 512]);
    }
    for (int sl = wave; sl < WSLOT; sl += 4) {
      const int idx = sl * 64 + lane;
      const int row = idx >> 2;
      const int kc = (idx & 3) ^ ((row >> 1) & 3);
      const int wrow = (n0 + row < N) ? row : 0;
      gload_lds16(W + (size_t)(n0 + wrow) * K + k0 + kc * 8, &Ws[buf][sl * 512]);
    }
  };

  const int npre = nk < 3 ? nk : 3;
  for (int p = 0; p < npre; p++) stage(p, k_beg + p * 32);

  for (int ki = 0; ki < nk; ki++) {
    const int rem = nk - 1 - ki;
    if (rem >= 2)
      asm volatile("s_waitcnt vmcnt(%0)" :: "n"(2 * LPS) : "memory");
    else if (rem == 1)
      asm volatile("s_waitcnt vmcnt(%0)" :: "n"(LPS) : "memory");
    else
      asm volatile("s_waitcnt vmcnt(0)" ::: "memory");
    __builtin_amdgcn_s_barrier();
    const int cur = ki & 3;
    half8 af[4], wf[NT];
#pragma unroll
    for (int i = 0; i < 4; i++)
      af[i] = *(const half8*)&As[cur][(wm + i * 16 + fr) * 32 + kp];
#pragma unroll
    for (int j = 0; j < NT; j++)
      wf[j] = *(const half8*)&Ws[cur][(wn + j * 16 + fr) * 32 + kp];
    __builtin_amdgcn_s_setprio(1);
#pragma unroll
    for (int i = 0; i < 4; i++)
#pragma unroll
      for (int j = 0; j < NT; j++)
        acc[i][j] = __builtin_amdgcn_mfma_f32_16x16x32_f16(af[i], wf[j], acc[i][j], 0, 0, 0);
    __builtin_amdgcn_s_setprio(0);
    if (ki + 3 < nk) stage((ki + 3) & 3, k_beg + (ki + 3) * 32);
  }

  const int col = lane & 15, rowq = lane >> 4;
#pragma unroll
  for (int i = 0; i < 4; i++) {
#pragma unroll
    for (int j = 0; j < NT; j++) {
      const int n = n0 + wn + j * 16 + col;
      if (n < N) {
#pragma unroll
        for (int r = 0; r < 4; r++) {
          const int m = m0 + wm + i * 16 + rowq * 4 + r;
          float v = acc[i][j][r];
          if (EPI == 0) {
            if (n < DI) ((_Float16*)Cv )[(size_t)m * DI + n]      = (_Float16)v;
            else        ((_Float16*)C2v)[(size_t)m * DI + n - DI] = (_Float16)v;
          } else if (EPI == 4) {
            ((_Float16*)Cv)[((size_t)bz * M + m) * ldc + n] = (_Float16)v;
          } else if (EPI == 5) {
            v += extra[n];
            v = (v > 20.f) ? v : __logf(1.f + __expf(v));
            ((_Float16*)Cv)[(size_t)m * ldc + n] = (_Float16)v;
          }
        }
      }
    }
  }
}

// ---------------------------------------------------------------------------
// Load per-channel A row; detect S4D-real init a[s] == -(s+1) (uniform).
// ---------------------------------------------------------------------------
__device__ __forceinline__ bool load_a(const float* __restrict__ A_log, int d,
                                       float* a) {
  const float4* Ap = (const float4*)(A_log + (size_t)d * DS);
  bool fast = true;
#pragma unroll
  for (int i = 0; i < 4; i++) {
    float4 v = Ap[i];
    a[4 * i + 0] = -__expf(v.x); a[4 * i + 1] = -__expf(v.y);
    a[4 * i + 2] = -__expf(v.z); a[4 * i + 3] = -__expf(v.w);
  }
#pragma unroll
  for (int s = 0; s < DS; s++)
    fast = fast && (fabsf(a[s] + (float)(s + 1)) < 1e-4f);
  return fast;
}

// ---------------------------------------------------------------------------
// R16 megakernel: whole MambaBlock, ONE regular launch + flag grid barrier.
// 512 blocks x 256 threads, 64 KB LDS -> exactly 2 blocks/CU (all resident).
// ---------------------------------------------------------------------------
__global__ __launch_bounds__(256, 2) void mega(MegaArgs P) {
  __shared__ alignas(16) _Float16 As[4][4096];   // 32 KB
  __shared__ alignas(16) _Float16 Ws[4][4096];   // 32 KB
  const int bid = blockIdx.x;
  const int t = threadIdx.x;

  // ---- P0: LayerNorm (grid-stride rows) + weight f2h ----
  {
    float* sAB = (float*)&Ws[0][0];   // 8 floats scratch
    for (int r = bid; r < MR; r += GRID) {
      const float* xr = P.x + (size_t)r * DM;
      float s = 0.f, ss = 0.f;
      for (int i = t; i < DM; i += NTH) {
        float v = xr[i];
        s += v; ss += v * v;
      }
      for (int o = 32; o > 0; o >>= 1) {
        s  += __shfl_down(s, o, 64);
        ss += __shfl_down(ss, o, 64);
      }
      const int wid = t >> 6, lid = t & 63;
      if (lid == 0) { sAB[wid] = s; sAB[4 + wid] = ss; }
      __syncthreads();
      if (t == 0) {
        float S  = sAB[0] + sAB[1] + sAB[2] + sAB[3];
        float SS = sAB[4] + sAB[5] + sAB[6] + sAB[7];
        float mu = S / DM;
        sAB[0] = mu;
        sAB[4] = rsqrtf(SS / DM - mu * mu + 1e-5f);
      }
      __syncthreads();
      const float mu = sAB[0], rs = sAB[4];
      for (int i = t; i < DM; i += NTH)
        P.h_h[(size_t)r * DM + i] = (_Float16)((xr[i] - mu) * rs * P.ln_w[i] + P.ln_b[i]);
      __syncthreads();   // protect sAB before next row's writes
    }
    const int N0 = 1048576, N1 = 524288, N2 = 49152, N3 = 32768;
    for (int i = bid * NTH + t; i < N0 + N1 + N2 + N3; i += GRID * NTH) {
      const float* s; _Float16* d; int off;
      if (i < N0)              { s = P.w_in;  d = P.w_in_h;  off = i; }
      else if (i < N0+N1)      { s = P.w_out; d = P.w_out_h; off = i - N0; }
      else if (i < N0+N1+N2)   { s = P.w_xp;  d = P.w_xp_h;  off = i - N0 - N1; }
      else                     { s = P.w_dt;  d = P.w_dt_h;  off = i - N0 - N1 - N2; }
      float4 v = ((const float4*)s)[off];
      half4v h = {(_Float16)v.x, (_Float16)v.y, (_Float16)v.z, (_Float16)v.w};
      ((half4v*)d)[off] = h;
    }
  }
  gsync(P.bar, 1);

  // ---- P1: in_proj GEMM (grid (32,16)) ----
  gemm_phase<0, 128>(P.h_h, P.w_in_h, P.xin, P.z, nullptr, 0,
                     MR, 2 * DI, DM, DM, bid & 31, bid >> 5, 0, As, Ws);
  gsync(P.bar, 2);

  // ---- P2: depthwise causal conv1d + SiLU (8 ch/thread) ----
  for (int idx = bid * NTH + t; idx < MR * DI / 8; idx += GRID * NTH) {
    const int d8 = idx & (DI / 8 - 1);
    const int ml = idx >> 8;
    const int l  = ml & (LL - 1);
    const int d0 = d8 * 8;
    half8 xr[4];
    const half8 zero = {0, 0, 0, 0, 0, 0, 0, 0};
#pragma unroll
    for (int k = 0; k < 4; k++) {
      const int lp = l - 3 + k;
      xr[k] = (lp >= 0) ? *(const half8*)&P.xin[(size_t)(ml - 3 + k) * DI + d0] : zero;
    }
    half8 o;
#pragma unroll
    for (int j = 0; j < 8; j++) {
      float acc = P.conv_b[d0 + j];
#pragma unroll
      for (int k = 0; k < 4; k++)
        acc += (float)xr[k][j] * P.conv_w[(d0 + j) * 4 + k];
      o[j] = (_Float16)(acc / (1.f + __expf(-acc)));
    }
    *(half8*)&P.xc[(size_t)ml * DI + d0] = o;
  }
  gsync(P.bar, 3);

  // ---- P3: x_proj GEMM (grid (1,16,16), split-K 16; half the blocks) ----
  if (bid < 256)
    gemm_phase<4, 96>(P.xc, P.w_xp_h, P.xp_part, nullptr, nullptr, XDBL,
                      MR, XDBL, DI, DI / 16, 0, bid & 15, bid >> 4, As, Ws);
  gsync(P.bar, 4);

  // ---- P4: x_proj partial reduce (f32 x_dbl + f16 dtr) ----
  for (int idx = bid * NTH + t; idx < MR * XDBL; idx += GRID * NTH) {
    const int m = idx / XDBL, c = idx - m * XDBL;
    float s = 0.f;
#pragma unroll
    for (int zz = 0; zz < 16; zz++)
      s += (float)P.xp_part[(size_t)zz * (MR * XDBL) + idx];
    P.x_dbl[idx] = s;
    if (c < DTR) P.dtr[m * DTR + c] = (_Float16)s;
  }
  gsync(P.bar, 5);

  // ---- P5: dt GEMM + softplus (grid (32,16)) ----
  gemm_phase<5, 64>(P.dtr, P.w_dt_h, P.dtb, nullptr, P.dt_proj_b, DI,
                    MR, DI, DTR, DTR, bid & 31, bid >> 5, 0, As, Ws);
  gsync(P.bar, 6);

  // ---- P6: scan phase 1 (local chunk scans) ----
  {
    float (*Bs)[DS] = (float(*)[DS])&As[0][0];   // 2 KB
    const int dblk = bid & 7;
    const int c = (bid >> 3) & (NC - 1);
    const int b = bid >> 8;
    const int d = dblk * 256 + t;
    const int mlbase = b * LL + c * CL;
    for (int i = t; i < CL * DS; i += NTH) {
      int tt = i >> 4, s = i & 15;
      Bs[tt][s] = P.x_dbl[(size_t)(mlbase + tt) * XDBL + DTR + s];
    }
    float a[DS];
    const bool fast = load_a(P.A_log, d, a);
    float h[DS];
#pragma unroll
    for (int s = 0; s < DS; s++) h[s] = 0.f;
    float S = 0.f;
    __syncthreads();
    if (fast) {
      for (int tt = 0; tt < CL; tt++) {
        const size_t ml = mlbase + tt;
        const float dtv = (float)P.dtb[ml * DI + d];
        const float u   = (float)P.xc[ml * DI + d];
        const float du  = dtv * u;
        S += dtv;
        const float r = __expf(-dtv);
        float Pp = 1.f;
#pragma unroll
        for (int s = 0; s < DS; s++) {
          Pp *= r;
          h[s] = Pp * h[s] + du * Bs[tt][s];
        }
      }
    } else {
      for (int tt = 0; tt < CL; tt++) {
        const size_t ml = mlbase + tt;
        const float dtv = (float)P.dtb[ml * DI + d];
        const float u   = (float)P.xc[ml * DI + d];
        const float du  = dtv * u;
        S += dtv;
#pragma unroll
        for (int s = 0; s < DS; s++)
          h[s] = __expf(dtv * a[s]) * h[s] + du * Bs[tt][s];
      }
    }
    const size_t base = ((size_t)(b * NC + c) * DS) * DI + d;
#pragma unroll
    for (int s = 0; s < DS; s++) P.HE[base + (size_t)s * DI] = h[s];
    P.SA[(size_t)(b * NC + c) * DI + d] = S;
  }
  gsync(P.bar, 7);

  // ---- P7: scan phase 2 (sequential chunk combine; 256 blocks' work) ----
  if (bid < 256) {
    const int idx = bid * NTH + t;    // NB*DS*DI = 65536
    const int d = idx & (DI - 1);
    const int s = (idx >> 11) & (DS - 1);
    const int b = idx >> 15;
    const float a = -__expf(P.A_log[(size_t)d * DS + s]);
    float Hc = 0.f;
    for (int c = 0; c < NC; c++) {
      const size_t o = ((size_t)(b * NC + c) * DS + s) * DI + d;
      const float he = P.HE[o];
      const float Pp = __expf(a * P.SA[(size_t)(b * NC + c) * DI + d]);
      P.HE[o] = Hc;
      Hc = Pp * Hc + he;
    }
  }
  gsync(P.bar, 8);

  // ---- P8: scan phase 3 (carry-in re-scan + fused y output) ----
  {
    float (*Bs)[DS] = (float(*)[DS])&As[0][0];
    float (*Cs)[DS] = (float(*)[DS])((char*)&As[0][0] + 2048);
    const int dblk = bid & 7;
    const int c = (bid >> 3) & (NC - 1);
    const int b = bid >> 8;
    const int d = dblk * 256 + t;
    const int mlbase = b * LL + c * CL;
    for (int i = t; i < CL * DS; i += NTH) {
      int tt = i >> 4, s = i & 15;
      const size_t ro = (size_t)(mlbase + tt) * XDBL + DTR + s;
      Bs[tt][s] = P.x_dbl[ro];
      Cs[tt][s] = P.x_dbl[ro + DS];
    }
    float a[DS];
    const bool fast = load_a(P.A_log, d, a);
    float h[DS];
    const size_t base = ((size_t)(b * NC + c) * DS) * DI + d;
#pragma unroll
    for (int s = 0; s < DS; s++) h[s] = P.HE[base + (size_t)s * DI];
    const float Dv = P.Dvec[d];
    __syncthreads();
    if (fast) {
      for (int tt = 0; tt < CL; tt++) {
        const size_t ml = mlbase + tt;
        const float dtv = (float)P.dtb[ml * DI + d];
        const float u   = (float)P.xc[ml * DI + d];
        const float du  = dtv * u;
        const float r = __expf(-dtv);
        float Pp = 1.f, p = 0.f;
#pragma unroll
        for (int s = 0; s < DS; s++) {
          Pp *= r;
          h[s] = Pp * h[s] + du * Bs[tt][s];
          p += h[s] * Cs[tt][s];
        }
        const float zv = (float)P.z[ml * DI + d];
        const float sil = zv / (1.f + __expf(-zv));
        P.y[ml * DI + d] = (_Float16)((p + u * Dv) * sil);
      }
    } else {
      for (int tt = 0; tt < CL; tt++) {
        const size_t ml = mlbase + tt;
        const float dtv = (float)P.dtb[ml * DI + d];
        const float u   = (float)P.xc[ml * DI + d];
        const float du  = dtv * u;
        float p = 0.f;
#pragma unroll
        for (int s = 0; s < DS; s++) {
          h[s] = __expf(dtv * a[s]) * h[s] + du * Bs[tt][s];
          p += h[s] * Cs[tt][s];
        }
        const float zv = (float)P.z[ml * DI + d];
        const float sil = zv / (1.f + __expf(-zv));
        P.y[ml * DI + d] = (_Float16)((p + u * Dv) * sil);
      }
    }
  }
  gsync(P.bar, 9);

  // ---- P9: out_proj GEMM (grid (8,16,4), split-K 4) ----
  gemm_phase<4, 128>(P.y, P.w_out_h, P.out_part, nullptr, nullptr, DM,
                     MR, DM, DI, DI / 4, bid & 7, (bid >> 3) & 15, bid >> 7, As, Ws);
  gsync(P.bar, 10);

  // ---- P10: residual + partial reduce ----
  for (int i = bid * NTH + t; i < MR * DM / 4; i += GRID * NTH) {
    float4 v = ((const float4*)P.x)[i];
#pragma unroll
    for (int zz = 0; zz < 4; zz++) {
      half4v p = ((const half4v*)(P.out_part + (size_t)zz * MR * DM))[i];
      v.x += (float)p.x; v.y += (float)p.y; v.z += (float)p.z; v.w += (float)p.w;
    }
    ((float4*)P.out)[i] = v;
  }
}

// ---------------------------------------------------------------------------
// Launch: memset barrier state + single regular dispatch.
// ---------------------------------------------------------------------------
extern "C" void kernel_launch(void* const* d_in, const int* in_sizes, int n_in,
                              void* d_out, int out_size, void* d_ws, size_t ws_size,
                              hipStream_t stream) {
  const float* x         = (const float*)d_in[0];
  const float* ln_w      = (const float*)d_in[1];
  const float* ln_b      = (const float*)d_in[2];
  const float* in_proj_w = (const float*)d_in[3];   // (4096, 1024)
  const float* conv_w    = (const float*)d_in[4];   // (2048, 1, 4)
  const float* conv_b    = (const float*)d_in[5];
  const float* x_proj_w  = (const float*)d_in[6];   // (96, 2048)
  const float* dt_proj_w = (const float*)d_in[7];   // (2048, 64)
  const float* dt_proj_b = (const float*)d_in[8];
  const float* A_log     = (const float*)d_in[9];   // (2048, 16)
  const float* Dvec      = (const float*)d_in[10];
  const float* out_proj_w= (const float*)d_in[11];  // (1024, 2048)
  float* out = (float*)d_out;

  // workspace layout (bytes). Aliasing:
  //   y aliases xin (xin dead after conv/P2; y written P8, read P9)
  //   xp_part aliases xin too (lives only P3->P4, inside xin's dead window)
  //   out_part aliases dtb (dtb dead after P8)
  // Barrier state (4 KB: gen + 512 flags) in the freed tail at 69337088.
  char* ws = (char*)d_ws;
  _Float16* h_h      = (_Float16*)ws;                 //  4 MB
  _Float16* xin_h    = (_Float16*)(ws + 4194304);     //  8 MB
  _Float16* y_h      = xin_h;
  _Float16* xp_part  = xin_h;                         //  6 MB (16 x MR x 96 f16)
  _Float16* z_h      = (_Float16*)(ws + 12582912);    //  8 MB
  _Float16* xc_h     = (_Float16*)(ws + 20971520);    //  8 MB
  _Float16* dtb_h    = (_Float16*)(ws + 29360128);    //  8 MB
  _Float16* out_part = dtb_h;                         // 16 MB (4 x MR*DM f16)
  float*    x_dbl    = (float*)   (ws + 46137344);    //  0.75 MB
  float*    SA       = (float*)   (ws + 46923776);    //  0.5 MB
  _Float16* dtr_h    = (_Float16*)(ws + 47448064);    //  0.25 MB
  float*    HE       = (float*)   (ws + 47710208);    //  8 MB
  _Float16* w_in_h   = (_Float16*)(ws + 56098816);    //  8 MB
  _Float16* w_out_h  = (_Float16*)(ws + 64487424);    //  4 MB
  _Float16* w_xp_h   = (_Float16*)(ws + 68681728);    //  0.375 MB
  _Float16* w_dt_h   = (_Float16*)(ws + 69074944);    //  0.25 MB
  unsigned* bar      = (unsigned*)(ws + 69337088);    //  4 KB barrier state

  hipMemsetAsync(bar, 0, 4096, stream);

  MegaArgs P;
  P.x = x; P.ln_w = ln_w; P.ln_b = ln_b;
  P.w_in = in_proj_w; P.w_out = out_proj_w; P.w_xp = x_proj_w; P.w_dt = dt_proj_w;
  P.conv_w = conv_w; P.conv_b = conv_b; P.dt_proj_b = dt_proj_b;
  P.A_log = A_log; P.Dvec = Dvec;
  P.h_h = h_h; P.w_in_h = w_in_h; P.w_out_h = w_out_h; P.w_xp_h = w_xp_h;
  P.w_dt_h = w_dt_h;
  P.xin = xin_h; P.z = z_h; P.xc = xc_h; P.dtb = dtb_h; P.dtr = dtr_h;
  P.xp_part = xp_part; P.out_part = out_part; P.y = y_h;
  P.x_dbl = x_dbl; P.SA = SA; P.HE = HE; P.out = out;
  P.bar = bar;

  mega<<<dim3(GRID), dim3(NTH), 0, stream>>>(P);
}

// Round 5
// 265.087 us; speedup vs baseline: 3.7612x; 1.6064x over previous
//
#include <hip/hip_runtime.h>
#include <hip/hip_bf16.h>
#include <math.h>

// Problem constants (from reference)
#define DM   1024        // d_model
#define DI   2048        // d_inner
#define DS   16          // d_state
#define DTR  64          // dt_rank
#define NB   2           // batch
#define LL   1024        // seq len
#define MR   (NB*LL)     // 2048 rows (b*l flattened)
#define XDBL 96          // dt_rank + 2*d_state
#define NC   16          // scan chunks (R17: 32 -> 16, halves HE traffic)
#define CL   64          // chunk length (NC*CL == LL)

typedef _Float16 half8  __attribute__((ext_vector_type(8)));
typedef _Float16 half4v __attribute__((ext_vector_type(4)));
typedef float    floatx4 __attribute__((ext_vector_type(4)));

__device__ __forceinline__ void gload_lds16(const void* g, void* l) {
  __builtin_amdgcn_global_load_lds(
      (const __attribute__((address_space(1))) void*)g,
      (__attribute__((address_space(3))) void*)l, 16, 0, 0);
}

// ---------------------------------------------------------------------------
// Front kernel: LN (blocks 0..2047) + out=x prefill + weight f2h.
// R17: writes out = x while x rows are in flight (enables atomic out_proj,
// removing the out_reduce kernel + 32 MB of partial traffic).
// ---------------------------------------------------------------------------
__global__ __launch_bounds__(256) void front_kernel(
    const float* __restrict__ x, const float* __restrict__ ln_w,
    const float* __restrict__ ln_b,
    const float* __restrict__ w_in, const float* __restrict__ w_out,
    const float* __restrict__ w_xp, const float* __restrict__ w_dt,
    _Float16* __restrict__ h_h, float* __restrict__ out,
    _Float16* __restrict__ w_in_h, _Float16* __restrict__ w_out_h,
    _Float16* __restrict__ w_xp_h, _Float16* __restrict__ w_dt_h) {
  const int blk = blockIdx.x;
  if (blk < MR) {
    __shared__ float sA[4], sB[4];
    const float* xr = x + (size_t)blk * DM;
    float s = 0.f, ss = 0.f;
    for (int i = threadIdx.x; i < DM; i += 256) {
      float v = xr[i];
      s += v; ss += v * v;
    }
    for (int o = 32; o > 0; o >>= 1) {
      s  += __shfl_down(s, o, 64);
      ss += __shfl_down(ss, o, 64);
    }
    const int wid = threadIdx.x >> 6, lid = threadIdx.x & 63;
    if (lid == 0) { sA[wid] = s; sB[wid] = ss; }
    __syncthreads();
    if (threadIdx.x == 0) {
      float S = sA[0] + sA[1] + sA[2] + sA[3];
      float SS = sB[0] + sB[1] + sB[2] + sB[3];
      float mu = S / DM;
      sA[0] = mu;
      sB[0] = rsqrtf(SS / DM - mu * mu + 1e-5f);
    }
    __syncthreads();
    const float mu = sA[0], rs = sB[0];
    for (int i = threadIdx.x; i < DM; i += 256) {
      const float v = xr[i];
      out[(size_t)blk * DM + i] = v;          // residual prefill
      h_h[(size_t)blk * DM + i] = (_Float16)((v - mu) * rs * ln_w[i] + ln_b[i]);
    }
    return;
  }
  int i = (blk - MR) * 256 + threadIdx.x;
  const int N0 = 1048576, N1 = 524288, N2 = 49152, N3 = 32768;
  const float* s; _Float16* d; int off;
  if (i < N0)            { s = w_in;  d = w_in_h;  off = i; }
  else if (i < N0+N1)    { s = w_out; d = w_out_h; off = i - N0; }
  else if (i < N0+N1+N2) { s = w_xp;  d = w_xp_h;  off = i - N0 - N1; }
  else if (i < N0+N1+N2+N3) { s = w_dt; d = w_dt_h; off = i - N0 - N1 - N2; }
  else return;
  float4 v = ((const float4*)s)[off];
  half4v h = {(_Float16)v.x, (_Float16)v.y, (_Float16)v.z, (_Float16)v.w};
  ((half4v*)d)[off] = h;
}

// ---------------------------------------------------------------------------
// MFMA f16 GEMM — R13's verified counted-vmcnt depth-3 pipeline.
// C[m,n] = sum_k A[m,k]*W[n,k], fp32 accumulate. Tile 128 x TN.
// 4 LDS buffers of 32-wide slabs; prologue stages up to 3; per iter:
//   vmcnt(2*LPS) -> s_barrier -> ds_read+MFMA(setprio) -> stage(i+3).
// EPI 0: dual f16 store (n<DI -> Cv else C2v, compact DI-wide rows)
// EPI 6: f32 atomicAdd into Cv[m*ldc+n]  (split-K partials, no reduce pass)
// ---------------------------------------------------------------------------
template <int EPI, int TN>
__global__ __launch_bounds__(256) void gemm_mfma(
    const _Float16* __restrict__ A,   // [M][K]
    const _Float16* __restrict__ W,   // [N][K]
    void* __restrict__ Cv, void* __restrict__ C2v, int ldc,
    int M, int N, int K, int kchunk) {
  constexpr int NT = (TN + 31) / 32;
  constexpr int WSLOT = TN / 16;
  constexpr int LPS = 2 + (WSLOT >= 8 ? 2 : 1);
  __shared__ alignas(16) _Float16 As[4][4096];
  __shared__ alignas(16) _Float16 Ws[4][4096];
  const int t = threadIdx.x;
  const int wave = t >> 6, lane = t & 63;
  const int m0 = blockIdx.y * 128, n0 = blockIdx.x * TN;
  const int k_beg = blockIdx.z * kchunk;
  const int nk = kchunk / 32;
  const int wm = (wave >> 1) * 64, wn = (wave & 1) * (TN / 2);
  floatx4 acc[4][NT];
#pragma unroll
  for (int i = 0; i < 4; i++)
#pragma unroll
    for (int j = 0; j < NT; j++) acc[i][j] = {0.f, 0.f, 0.f, 0.f};

  const int fr = lane & 15;
  const int kc8 = lane >> 4;
  const int kp = (kc8 ^ ((fr >> 1) & 3)) * 8;   // XOR bank swizzle

  auto stage = [&](int buf, int k0) {
    for (int sl = wave; sl < 8; sl += 4) {
      const int idx = sl * 64 + lane;
      const int row = idx >> 2;
      const int kc = (idx & 3) ^ ((row >> 1) & 3);
      gload_lds16(A + (size_t)(m0 + row) * K + k0 + kc * 8, &As[buf][sl * 512]);
    }
    for (int sl = wave; sl < WSLOT; sl += 4) {
      const int idx = sl * 64 + lane;
      const int row = idx >> 2;
      const int kc = (idx & 3) ^ ((row >> 1) & 3);
      const int wrow = (n0 + row < N) ? row : 0;
      gload_lds16(W + (size_t)(n0 + wrow) * K + k0 + kc * 8, &Ws[buf][sl * 512]);
    }
  };

  const int npre = nk < 3 ? nk : 3;
  for (int p = 0; p < npre; p++) stage(p, k_beg + p * 32);

  for (int ki = 0; ki < nk; ki++) {
    const int rem = nk - 1 - ki;
    if (rem >= 2)
      asm volatile("s_waitcnt vmcnt(%0)" :: "n"(2 * LPS) : "memory");
    else if (rem == 1)
      asm volatile("s_waitcnt vmcnt(%0)" :: "n"(LPS) : "memory");
    else
      asm volatile("s_waitcnt vmcnt(0)" ::: "memory");
    __builtin_amdgcn_s_barrier();
    const int cur = ki & 3;
    half8 af[4], wf[NT];
#pragma unroll
    for (int i = 0; i < 4; i++)
      af[i] = *(const half8*)&As[cur][(wm + i * 16 + fr) * 32 + kp];
#pragma unroll
    for (int j = 0; j < NT; j++)
      wf[j] = *(const half8*)&Ws[cur][(wn + j * 16 + fr) * 32 + kp];
    __builtin_amdgcn_s_setprio(1);
#pragma unroll
    for (int i = 0; i < 4; i++)
#pragma unroll
      for (int j = 0; j < NT; j++)
        acc[i][j] = __builtin_amdgcn_mfma_f32_16x16x32_f16(af[i], wf[j], acc[i][j], 0, 0, 0);
    __builtin_amdgcn_s_setprio(0);
    if (ki + 3 < nk) stage((ki + 3) & 3, k_beg + (ki + 3) * 32);
  }

  // epilogue: C/D layout col = lane&15, row = (lane>>4)*4 + reg
  const int col = lane & 15, rowq = lane >> 4;
#pragma unroll
  for (int i = 0; i < 4; i++) {
#pragma unroll
    for (int j = 0; j < NT; j++) {
      const int n = n0 + wn + j * 16 + col;
      if (n < N) {
#pragma unroll
        for (int r = 0; r < 4; r++) {
          const int m = m0 + wm + i * 16 + rowq * 4 + r;
          float v = acc[i][j][r];
          if (EPI == 0) {
            if (n < DI) ((_Float16*)Cv )[(size_t)m * DI + n]      = (_Float16)v;
            else        ((_Float16*)C2v)[(size_t)m * DI + n - DI] = (_Float16)v;
          } else if (EPI == 6) {
            atomicAdd(&((float*)Cv)[(size_t)m * ldc + n], v);
          }
        }
      }
    }
  }
}

// ---------------------------------------------------------------------------
// dt GEMM (R17): reads x_dbl f32 directly (no dtr intermediate).
// Tile 128 x 64, K = 64 = 2 slabs; A staged via f32 load + cvt + swizzled
// ds_write (same layout/XOR as gemm_mfma); W via gload_lds16. One barrier.
// Epilogue: softplus(acc + bias[n]) -> f16 dtb.
// ---------------------------------------------------------------------------
__global__ __launch_bounds__(256) void dt_kernel(
    const float* __restrict__ xdbl, const _Float16* __restrict__ W,
    const float* __restrict__ bias, _Float16* __restrict__ dtb) {
  __shared__ alignas(16) _Float16 As[2][4096];   // 2 slabs x 128 x 32
  __shared__ alignas(16) _Float16 Ws[2][2048];   // 2 slabs x 64 x 32
  const int t = threadIdx.x, wave = t >> 6, lane = t & 63;
  const int m0 = blockIdx.y * 128, n0 = blockIdx.x * 64;
  for (int q = wave; q < 16; q += 4) {           // A: 2 slabs x 8 slots
    const int ss = q >> 3, sl = q & 7;
    const int idx = sl * 64 + lane;
    const int row = idx >> 2;
    const int kc = (idx & 3) ^ ((row >> 1) & 3);
    const float* src = xdbl + (size_t)(m0 + row) * XDBL + ss * 32 + kc * 8;
    float4 a = ((const float4*)src)[0];
    float4 b = ((const float4*)src)[1];
    half8 h = {(_Float16)a.x, (_Float16)a.y, (_Float16)a.z, (_Float16)a.w,
               (_Float16)b.x, (_Float16)b.y, (_Float16)b.z, (_Float16)b.w};
    *(half8*)&As[ss][sl * 512 + lane * 8] = h;
  }
  for (int q = wave; q < 8; q += 4) {            // W: 2 slabs x 4 slots
    const int ss = q >> 2, sw = q & 3;
    const int idx = sw * 64 + lane;
    const int row = idx >> 2;
    const int kc = (idx & 3) ^ ((row >> 1) & 3);
    gload_lds16(W + (size_t)(n0 + row) * DTR + ss * 32 + kc * 8,
                &Ws[ss][sw * 512]);
  }
  asm volatile("s_waitcnt vmcnt(0)" ::: "memory");
  __syncthreads();
  const int fr = lane & 15, kc8 = lane >> 4;
  const int kp = (kc8 ^ ((fr >> 1) & 3)) * 8;
  const int wm = (wave >> 1) * 64, wn = (wave & 1) * 32;
  floatx4 acc[4][2];
#pragma unroll
  for (int i = 0; i < 4; i++)
#pragma unroll
    for (int j = 0; j < 2; j++) acc[i][j] = {0.f, 0.f, 0.f, 0.f};
#pragma unroll
  for (int ss = 0; ss < 2; ss++) {
    half8 af[4], wf[2];
#pragma unroll
    for (int i = 0; i < 4; i++)
      af[i] = *(const half8*)&As[ss][(wm + i * 16 + fr) * 32 + kp];
#pragma unroll
    for (int j = 0; j < 2; j++)
      wf[j] = *(const half8*)&Ws[ss][(wn + j * 16 + fr) * 32 + kp];
#pragma unroll
    for (int i = 0; i < 4; i++)
#pragma unroll
      for (int j = 0; j < 2; j++)
        acc[i][j] = __builtin_amdgcn_mfma_f32_16x16x32_f16(af[i], wf[j], acc[i][j], 0, 0, 0);
  }
  const int col = lane & 15, rowq = lane >> 4;
#pragma unroll
  for (int i = 0; i < 4; i++) {
#pragma unroll
    for (int j = 0; j < 2; j++) {
      const int n = n0 + wn + j * 16 + col;
#pragma unroll
      for (int r = 0; r < 4; r++) {
        const int m = m0 + wm + i * 16 + rowq * 4 + r;
        float v = acc[i][j][r] + bias[n];
        v = (v > 20.f) ? v : __logf(1.f + __expf(v));
        dtb[(size_t)m * DI + n] = (_Float16)v;
      }
    }
  }
}

// ---------------------------------------------------------------------------
// Depthwise causal conv1d (width 4) + bias + SiLU, 8 channels per thread.
// R17: also zeroes x_dbl for the atomic x_proj pass.
// ---------------------------------------------------------------------------
__global__ __launch_bounds__(256) void conv_silu_kernel(
    const _Float16* __restrict__ xin, const float* __restrict__ cw,
    const float* __restrict__ cb, _Float16* __restrict__ xc,
    float* __restrict__ xdbl) {
  const int idx = blockIdx.x * 256 + threadIdx.x;   // 0 .. MR*DI/8-1
  if (idx < MR * XDBL) xdbl[idx] = 0.f;
  const int d8 = idx & (DI / 8 - 1);
  const int ml = idx >> 8;
  const int l  = ml & (LL - 1);
  const int d0 = d8 * 8;
  half8 xr[4];
  const half8 zero = {0, 0, 0, 0, 0, 0, 0, 0};
#pragma unroll
  for (int k = 0; k < 4; k++) {
    const int lp = l - 3 + k;
    xr[k] = (lp >= 0) ? *(const half8*)&xin[(size_t)(ml - 3 + k) * DI + d0] : zero;
  }
  half8 o;
#pragma unroll
  for (int j = 0; j < 8; j++) {
    float acc = cb[d0 + j];
#pragma unroll
    for (int k = 0; k < 4; k++)
      acc += (float)xr[k][j] * cw[(d0 + j) * 4 + k];
    o[j] = (_Float16)(acc / (1.f + __expf(-acc)));
  }
  *(half8*)&xc[(size_t)ml * DI + d0] = o;
}

// ---------------------------------------------------------------------------
// Load per-channel A row; detect S4D-real init a[s] == -(s+1) (uniform).
// ---------------------------------------------------------------------------
__device__ __forceinline__ bool load_a(const float* __restrict__ A_log, int d,
                                       float* a) {
  const float4* Ap = (const float4*)(A_log + (size_t)d * DS);
  bool fast = true;
#pragma unroll
  for (int i = 0; i < 4; i++) {
    float4 v = Ap[i];
    a[4 * i + 0] = -__expf(v.x); a[4 * i + 1] = -__expf(v.y);
    a[4 * i + 2] = -__expf(v.z); a[4 * i + 3] = -__expf(v.w);
  }
#pragma unroll
  for (int s = 0; s < DS; s++)
    fast = fast && (fabsf(a[s] + (float)(s + 1)) < 1e-4f);
  return fast;
}

// ---------------------------------------------------------------------------
// Chunked selective scan, phase 1: per-(b,chunk) local scan with h=0 init.
// Fast path: exp(dt*a[s]) = r^(s+1), r = exp(-dt)  (1 exp + 15 mul vs 16 exp).
// R17: CL=64 (NC=16) — halves HE traffic.
// ---------------------------------------------------------------------------
__global__ __launch_bounds__(256) void scan_phase1(
    const _Float16* __restrict__ xc,  // x_conv (MR x DI) f16
    const float* __restrict__ xdbl,   // (MR x 96)
    const _Float16* __restrict__ dtm, // dt after softplus (MR x DI) f16
    const float* __restrict__ A_log,
    float* __restrict__ HE,           // (NB*NC*DS) x DI
    float* __restrict__ SA) {         // (NB*NC) x DI
  __shared__ float Bs[CL][DS];
  const int bi = blockIdx.x;
  const int dblk = bi & 7;
  const int c = (bi >> 3) & (NC - 1);
  const int b = bi >> 7;
  const int t = threadIdx.x;
  const int d = dblk * 256 + t;
  const int mlbase = b * LL + c * CL;

  for (int i = t; i < CL * DS; i += 256) {
    int tt = i >> 4, s = i & 15;
    Bs[tt][s] = xdbl[(size_t)(mlbase + tt) * XDBL + DTR + s];
  }

  float a[DS];
  const bool fast = load_a(A_log, d, a);
  float h[DS];
#pragma unroll
  for (int s = 0; s < DS; s++) h[s] = 0.f;
  float S = 0.f;
  __syncthreads();

  if (fast) {
    for (int tt = 0; tt < CL; tt++) {
      const size_t ml = mlbase + tt;
      const float dtv = (float)dtm[ml * DI + d];
      const float u   = (float)xc[ml * DI + d];
      const float du  = dtv * u;
      S += dtv;
      const float r = __expf(-dtv);
      float P = 1.f;
#pragma unroll
      for (int s = 0; s < DS; s++) {
        P *= r;
        h[s] = P * h[s] + du * Bs[tt][s];
      }
    }
  } else {
    for (int tt = 0; tt < CL; tt++) {
      const size_t ml = mlbase + tt;
      const float dtv = (float)dtm[ml * DI + d];
      const float u   = (float)xc[ml * DI + d];
      const float du  = dtv * u;
      S += dtv;
#pragma unroll
      for (int s = 0; s < DS; s++)
        h[s] = __expf(dtv * a[s]) * h[s] + du * Bs[tt][s];
    }
  }
  const size_t base = ((size_t)(b * NC + c) * DS) * DI + d;
#pragma unroll
  for (int s = 0; s < DS; s++) HE[base + (size_t)s * DI] = h[s];
  SA[(size_t)(b * NC + c) * DI + d] = S;
}

// ---------------------------------------------------------------------------
// Phase 2: sequential combine over chunk aggregates; HE becomes carry-in.
// ---------------------------------------------------------------------------
__global__ __launch_bounds__(256) void scan_phase2(
    const float* __restrict__ A_log,
    const float* __restrict__ SA,
    float* __restrict__ HE) {
  const int idx = blockIdx.x * 256 + threadIdx.x;  // NB*DS*DI
  const int d = idx & (DI - 1);
  const int s = (idx >> 11) & (DS - 1);
  const int b = idx >> 15;
  const float a = -__expf(A_log[(size_t)d * DS + s]);
  float Hc = 0.f;
  for (int c = 0; c < NC; c++) {
    const size_t o = ((size_t)(b * NC + c) * DS + s) * DI + d;
    const float he = HE[o];
    const float P = __expf(a * SA[(size_t)(b * NC + c) * DI + d]);
    HE[o] = Hc;
    Hc = P * Hc + he;
  }
}

// ---------------------------------------------------------------------------
// Phase 3: re-run chunks with carry-in; fuse y = (sum_s h*C + u*D)*silu(z).
// ---------------------------------------------------------------------------
__global__ __launch_bounds__(256) void scan_phase3(
    const _Float16* __restrict__ xc,
    const float* __restrict__ xdbl,
    const _Float16* __restrict__ dtm,   // f16
    const _Float16* __restrict__ zbuf,  // z (MR x DI) f16
    const float* __restrict__ A_log,
    const float* __restrict__ Dvec,
    const float* __restrict__ HE,
    _Float16* __restrict__ y) {         // (MR x DI) f16
  __shared__ float Bs[CL][DS];
  __shared__ float Cs[CL][DS];
  const int bi = blockIdx.x;
  const int dblk = bi & 7;
  const int c = (bi >> 3) & (NC - 1);
  const int b = bi >> 7;
  const int t = threadIdx.x;
  const int d = dblk * 256 + t;
  const int mlbase = b * LL + c * CL;

  for (int i = t; i < CL * DS; i += 256) {
    int tt = i >> 4, s = i & 15;
    const size_t ro = (size_t)(mlbase + tt) * XDBL + DTR + s;
    Bs[tt][s] = xdbl[ro];
    Cs[tt][s] = xdbl[ro + DS];
  }

  float a[DS];
  const bool fast = load_a(A_log, d, a);
  float h[DS];
  const size_t base = ((size_t)(b * NC + c) * DS) * DI + d;
#pragma unroll
  for (int s = 0; s < DS; s++) h[s] = HE[base + (size_t)s * DI];
  const float Dv = Dvec[d];
  __syncthreads();

  if (fast) {
    for (int tt = 0; tt < CL; tt++) {
      const size_t ml = mlbase + tt;
      const float dtv = (float)dtm[ml * DI + d];
      const float u   = (float)xc[ml * DI + d];
      const float du  = dtv * u;
      const float r = __expf(-dtv);
      float P = 1.f, p = 0.f;
#pragma unroll
      for (int s = 0; s < DS; s++) {
        P *= r;
        h[s] = P * h[s] + du * Bs[tt][s];
        p += h[s] * Cs[tt][s];
      }
      const float zv = (float)zbuf[ml * DI + d];
      const float sil = zv / (1.f + __expf(-zv));
      y[ml * DI + d] = (_Float16)((p + u * Dv) * sil);
    }
  } else {
    for (int tt = 0; tt < CL; tt++) {
      const size_t ml = mlbase + tt;
      const float dtv = (float)dtm[ml * DI + d];
      const float u   = (float)xc[ml * DI + d];
      const float du  = dtv * u;
      float p = 0.f;
#pragma unroll
      for (int s = 0; s < DS; s++) {
        h[s] = __expf(dtv * a[s]) * h[s] + du * Bs[tt][s];
        p += h[s] * Cs[tt][s];
      }
      const float zv = (float)zbuf[ml * DI + d];
      const float sil = zv / (1.f + __expf(-zv));
      y[ml * DI + d] = (_Float16)((p + u * Dv) * sil);
    }
  }
}

// ---------------------------------------------------------------------------
// Launch (9 dispatches; reduces removed via atomic split-K epilogues)
// ---------------------------------------------------------------------------
extern "C" void kernel_launch(void* const* d_in, const int* in_sizes, int n_in,
                              void* d_out, int out_size, void* d_ws, size_t ws_size,
                              hipStream_t stream) {
  const float* x         = (const float*)d_in[0];
  const float* ln_w      = (const float*)d_in[1];
  const float* ln_b      = (const float*)d_in[2];
  const float* in_proj_w = (const float*)d_in[3];   // (4096, 1024)
  const float* conv_w    = (const float*)d_in[4];   // (2048, 1, 4)
  const float* conv_b    = (const float*)d_in[5];
  const float* x_proj_w  = (const float*)d_in[6];   // (96, 2048)
  const float* dt_proj_w = (const float*)d_in[7];   // (2048, 64)
  const float* dt_proj_b = (const float*)d_in[8];
  const float* A_log     = (const float*)d_in[9];   // (2048, 16)
  const float* Dvec      = (const float*)d_in[10];
  const float* out_proj_w= (const float*)d_in[11];  // (1024, 2048)
  float* out = (float*)d_out;

  // workspace layout (bytes). y aliases xin (xin dead after conv).
  char* ws = (char*)d_ws;
  _Float16* h_h      = (_Float16*)ws;                 //  4 MB
  _Float16* xin_h    = (_Float16*)(ws + 4194304);     //  8 MB
  _Float16* y_h      = xin_h;
  _Float16* z_h      = (_Float16*)(ws + 12582912);    //  8 MB
  _Float16* xc_h     = (_Float16*)(ws + 20971520);    //  8 MB
  _Float16* dtb_h    = (_Float16*)(ws + 29360128);    //  8 MB
  float*    x_dbl    = (float*)   (ws + 46137344);    //  0.75 MB
  float*    SA       = (float*)   (ws + 46923776);    //  0.25 MB
  float*    HE       = (float*)   (ws + 47710208);    //  4 MB
  _Float16* w_in_h   = (_Float16*)(ws + 56098816);    //  8 MB
  _Float16* w_out_h  = (_Float16*)(ws + 64487424);    //  4 MB
  _Float16* w_xp_h   = (_Float16*)(ws + 68681728);    //  0.375 MB
  _Float16* w_dt_h   = (_Float16*)(ws + 69074944);    //  0.25 MB

  // 1. layernorm + out=x prefill + weight f2h
  front_kernel<<<MR + 6464, 256, 0, stream>>>(
      x, ln_w, ln_b, in_proj_w, out_proj_w, x_proj_w, dt_proj_w,
      h_h, out, w_in_h, w_out_h, w_xp_h, w_dt_h);

  // 2. in_proj: N=4096, tile 128x128, deep-pipelined, 512 blocks
  gemm_mfma<0, 128><<<dim3(2 * DI / 128, MR / 128, 1), 256, 0, stream>>>(
      h_h, w_in_h, xin_h, z_h, 0, MR, 2 * DI, DM, DM);

  // 3. conv + silu -> xc_h (f16) + zero x_dbl
  conv_silu_kernel<<<(MR * DI / 8) / 256, 256, 0, stream>>>(
      xin_h, conv_w, conv_b, xc_h, x_dbl);

  // 4. x_proj: tile 128x96, split-K 32 (nk=2), atomicAdd f32 -> x_dbl
  gemm_mfma<6, 96><<<dim3(1, MR / 128, 32), 256, 0, stream>>>(
      xc_h, w_xp_h, x_dbl, nullptr, XDBL, MR, XDBL, DI, DI / 32);

  // 5. dt: direct from x_dbl f32, K=64, softplus -> f16 dtb
  dt_kernel<<<dim3(DI / 64, MR / 128), 256, 0, stream>>>(
      x_dbl, w_dt_h, dt_proj_b, dtb_h);

  // 6. chunked selective scan (CL=64)
  scan_phase1<<<NB * NC * (DI / 256), 256, 0, stream>>>(
      xc_h, x_dbl, dtb_h, A_log, HE, SA);
  scan_phase2<<<(NB * DS * DI) / 256, 256, 0, stream>>>(A_log, SA, HE);
  scan_phase3<<<NB * NC * (DI / 256), 256, 0, stream>>>(
      xc_h, x_dbl, dtb_h, z_h, A_log, Dvec, HE, y_h);

  // 7. out_proj: tile 128x128, split-K 4, atomicAdd f32 -> out (pre-filled x)
  gemm_mfma<6, 128><<<dim3(DM / 128, MR / 128, 4), 256, 0, stream>>>(
      y_h, w_out_h, out, nullptr, DM, MR, DM, DI, DI / 4);
}